// Round 1
// baseline (511.993 us; speedup 1.0000x reference)
//
#include <hip/hip_runtime.h>
#include <math.h>

namespace {

constexpr int B_      = 65536;
constexpr int OBS_DIM_= 85;
constexpr int FEAT_   = 8;
constexpr int NL_     = 5;
constexpr int NT_     = 10;
constexpr int INF_    = 64;
constexpr int HID_    = 64;
constexpr int NACT_   = 5;
constexpr float ALPHA_= 0.01f;

__device__ __forceinline__ float leaky(float x)    { return x > 0.0f ? x : ALPHA_ * x; }
__device__ __forceinline__ float sigmoidf(float x) { return 1.0f / (1.0f + __expf(-x)); }
// tanh(x) = 1 - 2/(exp(2x)+1); exp overflow -> inf -> 1, exp->0 -> -1 (correct limits)
__device__ __forceinline__ float tanh_fast(float x){ return 1.0f - 2.0f / (__expf(2.0f * x) + 1.0f); }

// ---------------------------------------------------------------------------
// Tiny precompute: Wa1[i] = sum_j W[i][j]*a[j], Wa2[i] = sum_j W[i][j]*a[64+j]
// This removes the (B,10,64)@(64,64) matmul entirely: Wh@a == h_mix@(W@a).
// ---------------------------------------------------------------------------
__global__ void precompute_Wa(const float* __restrict__ W,
                              const float* __restrict__ a,
                              float* __restrict__ Wa) {
  int i = threadIdx.x;  // 64 threads
  float s1 = 0.0f, s2 = 0.0f;
  #pragma unroll
  for (int j = 0; j < INF_; ++j) {
    float w = W[i * INF_ + j];
    s1 += w * a[j];
    s2 += w * a[INF_ + j];
  }
  Wa[i] = s1;
  Wa[INF_ + i] = s2;
}

// Per time-step t: two dots  Wh1[t]=leaky(obs_in[t]@w+b) . Wa1 ,  Wh2 likewise.
__device__ __forceinline__ void stage1_t(const float* __restrict__ ob, int t,
                                         const float* __restrict__ w,
                                         const float* __restrict__ bv,
                                         const float* __restrict__ Wa,
                                         float& s1, float& s2) {
  float ov[FEAT_];
  #pragma unroll
  for (int f = 0; f < FEAT_; ++f) {
    int j = t * FEAT_ + f + 4;        // obs_in[j] = o[(j+4) mod 80]
    if (j >= 80) j -= 80;
    ov[f] = ob[j];
  }
  float a1 = 0.0f, a2 = 0.0f;
  for (int i = 0; i < INF_; ++i) {    // weight addrs wave-uniform -> s_load
    float z = bv[i];
    #pragma unroll
    for (int f = 0; f < FEAT_; ++f) z += ov[f] * w[f * INF_ + i];
    float hm = leaky(z);
    a1 += hm * Wa[i];
    a2 += hm * Wa[INF_ + i];
  }
  s1 = a1; s2 = a2;
}

__global__ __launch_bounds__(256) void atom_rnn_fused(
    const float* __restrict__ obs, const float* __restrict__ hidden,
    const float* __restrict__ w_in0, const float* __restrict__ b_in0,
    const float* __restrict__ w_in1, const float* __restrict__ b_in1,
    const float* __restrict__ w_in2, const float* __restrict__ b_in2,
    const float* __restrict__ Wa,
    const float* __restrict__ w_o1, const float* __restrict__ b_o1,
    const float* __restrict__ w_o2, const float* __restrict__ b_o2,
    const float* __restrict__ w_o3, const float* __restrict__ b_o3,
    const float* __restrict__ w_fc1, const float* __restrict__ b_fc1,
    const float* __restrict__ w_ih, const float* __restrict__ w_hh,
    const float* __restrict__ b_ih, const float* __restrict__ b_hh,
    const float* __restrict__ w_fc2, const float* __restrict__ b_fc2,
    float* __restrict__ q_out, float* __restrict__ h_out) {

  const int b = blockIdx.x * blockDim.x + threadIdx.x;
  if (b >= B_) return;
  const float* ob = obs + (long)b * OBS_DIM_;

  // ---- Stage 1: Wh1[10], Wh2[10] ----
  float Wh1[NT_], Wh2[NT_];
  #pragma unroll
  for (int t = 0; t < NL_; ++t)        stage1_t(ob, t, w_in0, b_in0, Wa, Wh1[t], Wh2[t]);
  #pragma unroll
  for (int t = NL_; t < NT_ - 1; ++t)  stage1_t(ob, t, w_in1, b_in1, Wa, Wh1[t], Wh2[t]);
  stage1_t(ob, NT_ - 1, w_in2, b_in2, Wa, Wh1[NT_ - 1], Wh2[NT_ - 1]);

  // ---- Attention: e[i][j] = leaky(Wh1[i] + Wh2[j]) ----
  // att1 column softmaxes (shared across rows): softmax_k e[5+jj][k], k in [0,5)
  float colm[NL_], cols_[NL_];
  #pragma unroll
  for (int jj = 0; jj < NL_; ++jj) {
    float ev[NL_], m = -1e30f;
    #pragma unroll
    for (int k = 0; k < NL_; ++k) { ev[k] = leaky(Wh1[NL_ + jj] + Wh2[k]); m = fmaxf(m, ev[k]); }
    float s = 0.0f;
    #pragma unroll
    for (int k = 0; k < NL_; ++k) s += __expf(ev[k] - m);
    colm[jj] = m; cols_[jj] = s;
  }

  float hp3[NL_];
  #pragma unroll
  for (int r = 0; r < NL_; ++r) {
    float att[NT_];
    // att0 row r: softmax_j e[r][5+j]
    float ev[NL_], m = -1e30f;
    #pragma unroll
    for (int j = 0; j < NL_; ++j) { ev[j] = leaky(Wh1[r] + Wh2[NL_ + j]); m = fmaxf(m, ev[j]); }
    float s = 0.0f;
    #pragma unroll
    for (int j = 0; j < NL_; ++j) { float e = __expf(ev[j] - m); att[j] = e; s += e; }
    float inv = 1.0f / s;
    #pragma unroll
    for (int j = 0; j < NL_; ++j) att[j] *= inv;
    // att1 part: exp(e[5+jj][r]-colm)/cols
    #pragma unroll
    for (int jj = 0; jj < NL_; ++jj) {
      float e = leaky(Wh1[NL_ + jj] + Wh2[r]);
      att[NL_ + jj] = __expf(e - colm[jj]) / cols_[jj];
    }
    // 10 -> 32 -> 16 -> 1 MLP
    float h1v[32];
    for (int c = 0; c < 32; ++c) {
      float z = b_o1[c];
      #pragma unroll
      for (int k = 0; k < NT_; ++k) z += att[k] * w_o1[k * 32 + c];
      h1v[c] = leaky(z);
    }
    float h2v[16];
    for (int c = 0; c < 16; ++c) {
      float z = b_o2[c];
      #pragma unroll
      for (int k = 0; k < 32; ++k) z += h1v[k] * w_o2[k * 16 + c];
      h2v[c] = leaky(z);
    }
    float z3 = b_o3[0];
    #pragma unroll
    for (int k = 0; k < 16; ++k) z3 += h2v[k] * w_o3[k];
    hp3[r] = leaky(z3);
  }

  // obs_out = softmax(hp3)
  float m5 = hp3[0];
  #pragma unroll
  for (int r = 1; r < NL_; ++r) m5 = fmaxf(m5, hp3[r]);
  float obs_out[NL_], ssum = 0.0f;
  #pragma unroll
  for (int r = 0; r < NL_; ++r) { obs_out[r] = __expf(hp3[r] - m5); ssum += obs_out[r]; }
  float sinv = 1.0f / ssum;
  #pragma unroll
  for (int r = 0; r < NL_; ++r) obs_out[r] *= sinv;

  // ---- fc1: x = relu([obs, obs_out] @ w_fc1 + b_fc1) ----
  float x[HID_];
  #pragma unroll
  for (int i = 0; i < HID_; ++i) x[i] = b_fc1[i];
  for (int k = 0; k < OBS_DIM_; ++k) {
    float o = ob[k];
    #pragma unroll
    for (int i = 0; i < HID_; ++i) x[i] += o * w_fc1[k * HID_ + i];
  }
  #pragma unroll
  for (int k = 0; k < NL_; ++k) {
    float o = obs_out[k];
    #pragma unroll
    for (int i = 0; i < HID_; ++i) x[i] += o * w_fc1[(OBS_DIM_ + k) * HID_ + i];
  }
  #pragma unroll
  for (int i = 0; i < HID_; ++i) x[i] = fmaxf(x[i], 0.0f);

  // ---- GRU, gate-row-wise (never materialize gi/gh[192]) + fused q ----
  float hv[HID_];
  #pragma unroll
  for (int i = 0; i < HID_; ++i) hv[i] = hidden[(long)b * HID_ + i];

  float q[NACT_];
  #pragma unroll
  for (int c = 0; c < NACT_; ++c) q[c] = b_fc2[c];

  for (int i = 0; i < HID_; ++i) {
    float gi_r = b_ih[i], gi_z = b_ih[HID_ + i], gi_n = b_ih[2 * HID_ + i];
    float gh_r = b_hh[i], gh_z = b_hh[HID_ + i], gh_n = b_hh[2 * HID_ + i];
    const float* wi_r = w_ih + (long)i * HID_;
    const float* wi_z = w_ih + (long)(HID_ + i) * HID_;
    const float* wi_n = w_ih + (long)(2 * HID_ + i) * HID_;
    const float* wh_r = w_hh + (long)i * HID_;
    const float* wh_z = w_hh + (long)(HID_ + i) * HID_;
    const float* wh_n = w_hh + (long)(2 * HID_ + i) * HID_;
    #pragma unroll
    for (int k = 0; k < HID_; ++k) {
      float xk = x[k], hk = hv[k];
      gi_r += xk * wi_r[k];
      gi_z += xk * wi_z[k];
      gi_n += xk * wi_n[k];
      gh_r += hk * wh_r[k];
      gh_z += hk * wh_z[k];
      gh_n += hk * wh_n[k];
    }
    float r_ = sigmoidf(gi_r + gh_r);
    float z_ = sigmoidf(gi_z + gh_z);
    float n_ = tanh_fast(gi_n + r_ * gh_n);
    float h_ = (1.0f - z_) * n_ + z_ * hv[i];
    h_out[(long)b * HID_ + i] = h_;
    #pragma unroll
    for (int c = 0; c < NACT_; ++c) q[c] += h_ * w_fc2[i * NACT_ + c];
  }
  #pragma unroll
  for (int c = 0; c < NACT_; ++c) q_out[(long)b * NACT_ + c] = q[c];
}

}  // namespace

extern "C" void kernel_launch(void* const* d_in, const int* in_sizes, int n_in,
                              void* d_out, int out_size, void* d_ws, size_t ws_size,
                              hipStream_t stream) {
  const float* obs    = (const float*)d_in[0];
  const float* hidden = (const float*)d_in[1];
  const float* w_in0  = (const float*)d_in[2];
  const float* b_in0  = (const float*)d_in[3];
  const float* w_in1  = (const float*)d_in[4];
  const float* b_in1  = (const float*)d_in[5];
  const float* w_in2  = (const float*)d_in[6];
  const float* b_in2  = (const float*)d_in[7];
  const float* W      = (const float*)d_in[8];
  const float* a      = (const float*)d_in[9];
  const float* w_o1   = (const float*)d_in[10];
  const float* b_o1   = (const float*)d_in[11];
  const float* w_o2   = (const float*)d_in[12];
  const float* b_o2   = (const float*)d_in[13];
  const float* w_o3   = (const float*)d_in[14];
  const float* b_o3   = (const float*)d_in[15];
  const float* w_fc1  = (const float*)d_in[16];
  const float* b_fc1  = (const float*)d_in[17];
  const float* w_ih   = (const float*)d_in[18];
  const float* w_hh   = (const float*)d_in[19];
  const float* b_ih   = (const float*)d_in[20];
  const float* b_hh   = (const float*)d_in[21];
  const float* w_fc2  = (const float*)d_in[22];
  const float* b_fc2  = (const float*)d_in[23];

  float* q_out = (float*)d_out;                  // (B, 5) flat
  float* h_out = q_out + (long)B_ * NACT_;       // (B, 64) flat

  float* Wa = (float*)d_ws;                      // 128 floats scratch

  precompute_Wa<<<1, 64, 0, stream>>>(W, a, Wa);
  atom_rnn_fused<<<B_ / 256, 256, 0, stream>>>(
      obs, hidden, w_in0, b_in0, w_in1, b_in1, w_in2, b_in2, Wa,
      w_o1, b_o1, w_o2, b_o2, w_o3, b_o3, w_fc1, b_fc1,
      w_ih, w_hh, b_ih, b_hh, w_fc2, b_fc2, q_out, h_out);
}